// Round 1
// baseline (99.086 us; speedup 1.0000x reference)
//
#include <hip/hip_runtime.h>

// Negative L1 cdist: out[n,m] = -sum_d |x[n,d] - w[m,d]|
// N=8192, M=1024, D=64, fp32.
//
// VALU-bound problem (no MFMA path for |a-b|). Floor ~13.7 us at 2 VALU
// ops per (n,m,d). Tiling: 128x128 per block, 8x8 per thread, d-major LDS.

constexpr int Mdim = 1024;
constexpr int Ddim = 64;
constexpr int BN = 128;     // n-tile
constexpr int BM = 128;     // m-tile
constexpr int DK = 32;      // d-chunk resident in LDS
constexpr int STR = 132;    // LDS row stride in floats (pad 128 -> 132)

__global__ __launch_bounds__(256, 2) void cdist_l1_kernel(
    const float* __restrict__ x, const float* __restrict__ w,
    float* __restrict__ out)
{
    // d-major tiles: l*[d][row], row = n (lx) or m (lw), stride STR
    __shared__ float lx[DK * STR];
    __shared__ float lw[DK * STR];

    const int t  = threadIdx.x;
    const int n0 = blockIdx.y * BN;
    const int m0 = blockIdx.x * BM;

    // ---- compute mapping: wave-quadrant 16x16 thread grid ----
    // Each thread: 8 consecutive n rows (ty..ty+7), m columns split as
    // {tx4..tx4+3} and {tx4+64..tx4+67} for contiguous float4 stores and
    // <=2-way LDS bank aliasing on every inner-loop read.
    const int wv = t >> 6;
    const int ln = t & 63;
    const int tx4 = ((ln & 7) + (wv & 1) * 8) * 4;   // 0..60
    const int ty  = ((ln >> 3) + (wv >> 1) * 8) * 8; // 0..120

    // ---- staging mapping ----
    const int c4 = t & 7;    // float4 index within a 32-d chunk
    const int r0 = t >> 3;   // 0..31 (row group)

    float acc[8][8];
#pragma unroll
    for (int i = 0; i < 8; ++i)
#pragma unroll
        for (int j = 0; j < 8; ++j) acc[i][j] = 0.0f;

    for (int kc = 0; kc < Ddim; kc += DK) {
        if (kc) __syncthreads();

        // stage 128 rows x 32 d of x and w, transposing to d-major
#pragma unroll
        for (int i = 0; i < 4; ++i) {
            const int row = r0 + i * 32;
            const float4 vx = *(const float4*)(x + (size_t)(n0 + row) * Ddim + kc + c4 * 4);
            const float4 vw = *(const float4*)(w + (size_t)(m0 + row) * Ddim + kc + c4 * 4);
            const int db = c4 * 4;
            lx[(db + 0) * STR + row] = vx.x;
            lx[(db + 1) * STR + row] = vx.y;
            lx[(db + 2) * STR + row] = vx.z;
            lx[(db + 3) * STR + row] = vx.w;
            lw[(db + 0) * STR + row] = vw.x;
            lw[(db + 1) * STR + row] = vw.y;
            lw[(db + 2) * STR + row] = vw.z;
            lw[(db + 3) * STR + row] = vw.w;
        }
        __syncthreads();

#pragma unroll 4
        for (int d = 0; d < DK; ++d) {
            const float4 a0 = *(const float4*)&lx[d * STR + ty];
            const float4 a1 = *(const float4*)&lx[d * STR + ty + 4];
            const float4 b0 = *(const float4*)&lw[d * STR + tx4];
            const float4 b1 = *(const float4*)&lw[d * STR + tx4 + 64];
            const float av[8] = {a0.x, a0.y, a0.z, a0.w, a1.x, a1.y, a1.z, a1.w};
            const float bv[8] = {b0.x, b0.y, b0.z, b0.w, b1.x, b1.y, b1.z, b1.w};
#pragma unroll
            for (int i = 0; i < 8; ++i)
#pragma unroll
                for (int j = 0; j < 8; ++j)
                    acc[i][j] -= fabsf(av[i] - bv[j]);  // v_sub + v_sub(abs mod)
        }
    }

    // ---- store: two contiguous float4 per row per thread ----
#pragma unroll
    for (int i = 0; i < 8; ++i) {
        float* p = out + (size_t)(n0 + ty + i) * Mdim + m0;
        const float4 o0 = {acc[i][0], acc[i][1], acc[i][2], acc[i][3]};
        const float4 o1 = {acc[i][4], acc[i][5], acc[i][6], acc[i][7]};
        *(float4*)(p + tx4)      = o0;
        *(float4*)(p + tx4 + 64) = o1;
    }
}

extern "C" void kernel_launch(void* const* d_in, const int* in_sizes, int n_in,
                              void* d_out, int out_size, void* d_ws, size_t ws_size,
                              hipStream_t stream) {
    const float* x = (const float*)d_in[0];   // [8192, 64] fp32
    const float* w = (const float*)d_in[1];   // [1024, 64] fp32
    float* out = (float*)d_out;               // [8192, 1024] fp32

    const int N = in_sizes[0] / Ddim;         // 8192
    const int M = in_sizes[1] / Ddim;         // 1024

    dim3 grid(M / BM, N / BN);                // (8, 64) = 512 blocks
    dim3 block(256);
    cdist_l1_kernel<<<grid, block, 0, stream>>>(x, w, out);
}

// Round 2
// 97.418 us; speedup vs baseline: 1.0171x; 1.0171x over previous
//
#include <hip/hip_runtime.h>
#include <math.h>

// Negative L1 cdist: out[n,m] = -sum_d |x[n,d] - w[m,d]|
// N=8192, M=1024, D=64, fp32.
//
// R1 post-mortem: latency-bound at 2 waves/SIMD (grid 512 blocks = 2 blocks/CU).
// R2: 64x128 block tile, 4x8 per thread -> 1024 blocks = 4 waves/SIMD.
// Register double-buffer of LDS fragments + chunk-2 global prefetch.
// Floors: VALU 13.7 us, LDS-issue 15.4 us.

constexpr int Mdim = 1024;
constexpr int Ddim = 64;
constexpr int BN = 64;      // n-tile
constexpr int BM = 128;     // m-tile
constexpr int DK = 32;      // d-chunk resident in LDS
constexpr int XS = 68;      // lx stride (64 + 4 pad) -> ty reads hit distinct banks
constexpr int WS = 132;     // lw stride (128 + 4 pad) -> tx reads 2-way (free)

__global__ __launch_bounds__(256, 4) void cdist_l1_kernel(
    const float* __restrict__ x, const float* __restrict__ w,
    float* __restrict__ out)
{
    // d-major tiles: l*[d][row]
    __shared__ float lx[DK * XS];   //  8.7 KB
    __shared__ float lw[DK * WS];   // 16.9 KB  (25.6 KB total)

    const int t  = threadIdx.x;
    const int n0 = blockIdx.y * BN;
    const int m0 = blockIdx.x * BM;

    // compute mapping: 16 m-columns x 16 n-rows of threads (4 waves)
    // thread tile: 4 n-rows (ty..ty+3), 8 m-cols ({tx4..+3} and {tx4+64..+67})
    const int wv  = t >> 6;
    const int ln  = t & 63;
    const int tx4 = (ln & 15) * 4;              // 0..60
    const int ty  = ((ln >> 4) + wv * 4) * 4;   // 0..60, wave-local quads

    // staging mapping: 8 float4 d-groups x 32 row-groups
    const int c4 = t & 7;
    const int rg = t >> 3;
    const int db = c4 * 4;

    float acc[4][8];
#pragma unroll
    for (int i = 0; i < 4; ++i)
#pragma unroll
        for (int j = 0; j < 8; ++j) acc[i][j] = 0.0f;

    auto load_chunk = [&](int kc, float4 (&vx)[2], float4 (&vw)[4]) {
#pragma unroll
        for (int i = 0; i < 2; ++i)
            vx[i] = *(const float4*)(x + (size_t)(n0 + rg + i * 32) * Ddim + kc + db);
#pragma unroll
        for (int i = 0; i < 4; ++i)
            vw[i] = *(const float4*)(w + (size_t)(m0 + rg + i * 32) * Ddim + kc + db);
    };

    auto stage = [&](const float4 (&vx)[2], const float4 (&vw)[4]) {
#pragma unroll
        for (int i = 0; i < 2; ++i) {
            const int row = rg + i * 32;
            lx[(db + 0) * XS + row] = vx[i].x;
            lx[(db + 1) * XS + row] = vx[i].y;
            lx[(db + 2) * XS + row] = vx[i].z;
            lx[(db + 3) * XS + row] = vx[i].w;
        }
#pragma unroll
        for (int i = 0; i < 4; ++i) {
            const int row = rg + i * 32;
            lw[(db + 0) * WS + row] = vw[i].x;
            lw[(db + 1) * WS + row] = vw[i].y;
            lw[(db + 2) * WS + row] = vw[i].z;
            lw[(db + 3) * WS + row] = vw[i].w;
        }
    };

    auto compute = [&]() {
        // software pipeline: fragments for d+1 in flight during compute of d
        float4 a_c  = *(const float4*)&lx[ty];
        float4 b0_c = *(const float4*)&lw[tx4];
        float4 b1_c = *(const float4*)&lw[tx4 + 64];
#pragma unroll 8
        for (int d = 0; d < DK; ++d) {
            float4 a_n  = {0, 0, 0, 0};
            float4 b0_n = {0, 0, 0, 0};
            float4 b1_n = {0, 0, 0, 0};
            if (d + 1 < DK) {
                a_n  = *(const float4*)&lx[(d + 1) * XS + ty];
                b0_n = *(const float4*)&lw[(d + 1) * WS + tx4];
                b1_n = *(const float4*)&lw[(d + 1) * WS + tx4 + 64];
            }
            const float av[4] = {a_c.x, a_c.y, a_c.z, a_c.w};
            const float bv[8] = {b0_c.x, b0_c.y, b0_c.z, b0_c.w,
                                 b1_c.x, b1_c.y, b1_c.z, b1_c.w};
#pragma unroll
            for (int i = 0; i < 4; ++i)
#pragma unroll
                for (int j = 0; j < 8; ++j)
                    acc[i][j] -= fabsf(av[i] - bv[j]);  // v_sub + v_sub(|.| mod)
            a_c = a_n; b0_c = b0_n; b1_c = b1_n;
        }
    };

    // ---- chunk 0 stage; chunk 1 globals issued before first compute ----
    float4 gx[2], gw[4];
    load_chunk(0, gx, gw);
    stage(gx, gw);
    float4 hx[2], hw[4];
    load_chunk(DK, hx, hw);        // in flight during chunk-0 compute
    __syncthreads();

    compute();
    __syncthreads();

    stage(hx, hw);
    __syncthreads();

    compute();

    // ---- store: two contiguous float4 per row per thread ----
#pragma unroll
    for (int i = 0; i < 4; ++i) {
        float* p = out + (size_t)(n0 + ty + i) * Mdim + m0;
        const float4 o0 = {acc[i][0], acc[i][1], acc[i][2], acc[i][3]};
        const float4 o1 = {acc[i][4], acc[i][5], acc[i][6], acc[i][7]};
        *(float4*)(p + tx4)      = o0;
        *(float4*)(p + tx4 + 64) = o1;
    }
}

extern "C" void kernel_launch(void* const* d_in, const int* in_sizes, int n_in,
                              void* d_out, int out_size, void* d_ws, size_t ws_size,
                              hipStream_t stream) {
    (void)d_ws; (void)ws_size; (void)n_in; (void)out_size;
    const float* x = (const float*)d_in[0];   // [8192, 64] fp32
    const float* w = (const float*)d_in[1];   // [1024, 64] fp32
    float* out = (float*)d_out;               // [8192, 1024] fp32

    const int N = in_sizes[0] / Ddim;         // 8192
    const int M = in_sizes[1] / Ddim;         // 1024

    dim3 grid(M / BM, N / BN);                // (8, 128) = 1024 blocks
    dim3 block(256);
    cdist_l1_kernel<<<grid, block, 0, stream>>>(x, w, out);
}